// Round 8
// baseline (72.969 us; speedup 1.0000x reference)
//
#include <hip/hip_runtime.h>

// Shapes (fixed by setup_inputs)
constexpr int N  = 4, C = 64, H = 16, W = 16;
constexpr int NF = 128;
constexpr int D  = C * 9;          // 576
constexpr float EPSF = 1e-5f;

// ---------------------------------------------------------------------------
// K1: s = conv3x3(x,w) fp64; t = 2r/(2s+eps).  Also emits w2f4 for K2 as a
// side job (288 elems/block, independent of this block's compute).
// Grid 256 = (n4, oh16, owg2, fhalf2): block = 8-wide ow strip x 64 filters.
// Threads 1024 = f(64) x cg(16); cg owns 4 channels = 36 consecutive w floats
// = 9 aligned float4 loads DIRECT from raw w (no relayout needed: offset
// fglob*2304B + cg*144B is 16B-aligned).  x staged fp32 [c][dh][12].
// Partials partd[cg][o][f] lane-contiguous (2-way fp64 alias = free).
// ---------------------------------------------------------------------------
__global__ void __launch_bounds__(1024) k_conv_t(
        const float* __restrict__ x, const float* __restrict__ w,
        const float* __restrict__ r, float* __restrict__ t_g,
        float* __restrict__ w2f4) {
    __shared__ float  xl[C * 36];           // 9.2 KB: [c][dh][12] (10 used)
    __shared__ double partd[16 * 8 * 64];   // 64 KB: [cg][o][f]

    const int bid = blockIdx.x;
    const int tid = threadIdx.x;

    // side job: produce K2's weight layout
    // w2f4[((fq*9+ab)*64 + c)*4 + j] = w[fq*4+j][c*9 + flip(ab)]
    if (tid < 288) {
        const int o = bid * 288 + tid;
        const int j = o & 3;
        const int c = (o >> 2) & 63, rest = o >> 8;
        const int ab = rest % 9, fq = rest / 9;
        const int a = ab / 3, b = ab % 3;
        w2f4[o] = w[(fq * 4 + j) * D + c * 9 + (2 - a) * 3 + (2 - b)];
    }

    const int fh  = bid & 1;
    const int ow0 = ((bid >> 1) & 1) * 8;
    const int oh  = (bid >> 2) & 15;
    const int n   = bid >> 6;
    const int f   = tid & 63;
    const int cg  = tid >> 6;               // 0..15

    for (int idx = tid; idx < C * 30; idx += 1024) {
        const int c = idx / 30, rem = idx % 30;
        const int dh = rem / 10, dw = rem % 10;
        const int ih = oh - 1 + dh, iw = ow0 - 1 + dw;
        float v = 0.f;
        if (ih >= 0 && ih < H && iw >= 0 && iw < W)
            v = x[((n * C + c) * H + ih) * W + iw];
        xl[c * 36 + dh * 12 + dw] = v;
    }
    __syncthreads();

    const int c0 = cg * 4;
    const int fglob = fh * 64 + f;
    // 36 consecutive floats of w for this (filter, 4-channel group): aligned.
    const float4* __restrict__ wp = (const float4*)(w + fglob * D + cg * 36);

    float wreg[36];
#pragma unroll
    for (int i = 0; i < 9; ++i) {
        const float4 wv = wp[i];
        wreg[i * 4 + 0] = wv.x; wreg[i * 4 + 1] = wv.y;
        wreg[i * 4 + 2] = wv.z; wreg[i * 4 + 3] = wv.w;
    }

    double acc[8];
#pragma unroll
    for (int o = 0; o < 8; ++o) acc[o] = 0.0;

#pragma unroll
    for (int cl = 0; cl < 4; ++cl) {
#pragma unroll
        for (int dh = 0; dh < 3; ++dh) {
            const float* rowp = xl + (c0 + cl) * 36 + dh * 12;
            const float4 xa = *(const float4*)rowp;
            const float4 xb = *(const float4*)(rowp + 4);
            const float2 xc = *(const float2*)(rowp + 8);
            double xd[10];
            xd[0] = (double)xa.x; xd[1] = (double)xa.y;
            xd[2] = (double)xa.z; xd[3] = (double)xa.w;
            xd[4] = (double)xb.x; xd[5] = (double)xb.y;
            xd[6] = (double)xb.z; xd[7] = (double)xb.w;
            xd[8] = (double)xc.x; xd[9] = (double)xc.y;
#pragma unroll
            for (int b = 0; b < 3; ++b) {
                const double wd = (double)wreg[cl * 9 + dh * 3 + b];
#pragma unroll
                for (int o = 0; o < 8; ++o)
                    acc[o] += wd * xd[b + o];
            }
        }
    }

#pragma unroll
    for (int o = 0; o < 8; ++o)
        partd[(cg * 8 + o) * 64 + f] = acc[o];
    __syncthreads();

    if (tid < 512) {
        const int f2 = tid & 63, o = tid >> 6;
        double s = 0.0;
#pragma unroll
        for (int g = 0; g < 16; ++g)
            s += partd[(g * 8 + o) * 64 + f2];
        const int fg2 = fh * 64 + f2;
        const int idx = ((n * NF + fg2) * H + oh) * W + ow0 + o;
        t_g[idx] = (float)((2.0 * (double)r[idx]) / (2.0 * s + (double)EPSF));
    }
}

// ---------------------------------------------------------------------------
// K2: out = x * convT3x3(t, w)
// Grid 256 = (n4, h16, wg2, chalf2): block = 8-wide w strip x 32 channels.
// Threads 1024 = c(32) x fg(32); fg owns 4 filters (one w2f4 quad).
// t staged [f][a][12] aligned.  Partials fpart[fg][o][c] lane-contiguous.
// ---------------------------------------------------------------------------
__global__ void __launch_bounds__(1024) k_convT_out(
        const float* __restrict__ x, const float4* __restrict__ w2f4,
        const float* __restrict__ t_g, float* __restrict__ out) {
    __shared__ float tl[NF * 36];           // 18.4 KB: [f][a][12] (10 used)
    __shared__ float fpart[32 * 8 * 32];    // 32.8 KB: [fg][o][c]

    const int bid = blockIdx.x;
    const int ch  = bid & 1;
    const int w0  = ((bid >> 1) & 1) * 8;
    const int h   = (bid >> 2) & 15;
    const int n   = bid >> 6;
    const int tid = threadIdx.x;
    const int c   = tid & 31;
    const int fg  = tid >> 5;               // 0..31

    for (int idx = tid; idx < NF * 30; idx += 1024) {
        const int ff = idx / 30, rem = idx % 30;
        const int a = rem / 10, ww = rem % 10;
        const int oh2 = h - 1 + a, ow = w0 - 1 + ww;
        float v = 0.f;
        if (oh2 >= 0 && oh2 < H && ow >= 0 && ow < W)
            v = t_g[((n * NF + ff) * H + oh2) * W + ow];
        tl[ff * 36 + a * 12 + ww] = v;
    }
    __syncthreads();

    const float4* __restrict__ wp = w2f4 + (fg * 9) * 64 + ch * 32 + c;
    float wq[36];
#pragma unroll
    for (int ab = 0; ab < 9; ++ab) {
        const float4 wv = wp[ab * 64];
        wq[ab * 4 + 0] = wv.x; wq[ab * 4 + 1] = wv.y;
        wq[ab * 4 + 2] = wv.z; wq[ab * 4 + 3] = wv.w;
    }

    float acc[8];
#pragma unroll
    for (int o = 0; o < 8; ++o) acc[o] = 0.f;

#pragma unroll
    for (int j = 0; j < 4; ++j) {
        const int fi = fg * 4 + j;
#pragma unroll
        for (int a = 0; a < 3; ++a) {
            const float* rowp = tl + fi * 36 + a * 12;
            const float4 ta = *(const float4*)rowp;
            const float4 tb = *(const float4*)(rowp + 4);
            const float2 tc = *(const float2*)(rowp + 8);
            const float tw[10] = {ta.x, ta.y, ta.z, ta.w,
                                  tb.x, tb.y, tb.z, tb.w, tc.x, tc.y};
#pragma unroll
            for (int b = 0; b < 3; ++b) {
                const float wv = wq[(a * 3 + b) * 4 + j];
#pragma unroll
                for (int o = 0; o < 8; ++o)
                    acc[o] += wv * tw[b + o];
            }
        }
    }

#pragma unroll
    for (int o = 0; o < 8; ++o)
        fpart[(fg * 8 + o) * 32 + c] = acc[o];
    __syncthreads();

    if (tid < 256) {
        const int c2 = tid & 31, o = tid >> 5;
        float s = 0.f;
#pragma unroll
        for (int g = 0; g < 32; ++g)
            s += fpart[(g * 8 + o) * 32 + c2];
        const int cglob = ch * 32 + c2;
        const int idx = ((n * C + cglob) * H + h) * W + w0 + o;
        out[idx] = x[idx] * s;
    }
}

// ---------------------------------------------------------------------------
extern "C" void kernel_launch(void* const* d_in, const int* in_sizes, int n_in,
                              void* d_out, int out_size, void* d_ws, size_t ws_size,
                              hipStream_t stream) {
    const float* x = (const float*)d_in[0];   // (4,64,16,16)
    const float* r = (const float*)d_in[1];   // (4,128,16,16)
    const float* w = (const float*)d_in[2];   // (128,64,3,3)
    float* out = (float*)d_out;               // (4,64,16,16)

    float* ws    = (float*)d_ws;
    float* w2f4  = ws;                        // 73728 floats (16B-aligned)
    float* t_g   = w2f4 + 73728;              // 131072 floats

    k_conv_t<<<256, 1024, 0, stream>>>(x, w, r, t_g, w2f4);
    k_convT_out<<<256, 1024, 0, stream>>>(x, (const float4*)w2f4, t_g, out);
}